// Round 15
// baseline (323.836 us; speedup 1.0000x reference)
//
#include <hip/hip_runtime.h>

#define NN 50000
#define NE 800000
#define NG 64
#define NCHUNK 64
#define CHUNK 12500     // NE / NCHUNK
#define HALF 25000      // NN / 2

typedef short short8 __attribute__((ext_vector_type(8)));
typedef float f32x4 __attribute__((ext_vector_type(4)));

// bf16 helpers (RTNE)
__device__ __forceinline__ unsigned short f2bf(float f) {
    unsigned int u = __float_as_uint(f);
    u = (u + 0x7FFFu + ((u >> 16) & 1u)) >> 16;
    return (unsigned short)u;
}
__device__ __forceinline__ float bf2f(unsigned short h) {
    return __uint_as_float((unsigned int)h << 16);
}
// accumulate 8 bf16 feats (one uint4) with weight w
__device__ __forceinline__ void fma8(float* acc, float w, const uint4 v) {
    const unsigned int u0 = v.x, u1 = v.y, u2 = v.z, u3 = v.w;
    acc[0] = fmaf(w, __uint_as_float(u0 << 16), acc[0]);
    acc[1] = fmaf(w, __uint_as_float(u0 & 0xFFFF0000u), acc[1]);
    acc[2] = fmaf(w, __uint_as_float(u1 << 16), acc[2]);
    acc[3] = fmaf(w, __uint_as_float(u1 & 0xFFFF0000u), acc[3]);
    acc[4] = fmaf(w, __uint_as_float(u2 << 16), acc[4]);
    acc[5] = fmaf(w, __uint_as_float(u2 & 0xFFFF0000u), acc[5]);
    acc[6] = fmaf(w, __uint_as_float(u3 << 16), acc[6]);
    acc[7] = fmaf(w, __uint_as_float(u3 & 0xFFFF0000u), acc[7]);
}

// ---------------- fused front-end: hist | cvtx | cvtw | zero (no cross-block coordination) ----------------
__global__ __launch_bounds__(1024) void k_prep(const float* __restrict__ x, const float* __restrict__ W1,
                                               const float* __restrict__ W2, const float* __restrict__ W3,
                                               const int* __restrict__ ei,
                                               unsigned short* __restrict__ xb,
                                               unsigned short* __restrict__ wt1, unsigned short* __restrict__ wt2,
                                               unsigned short* __restrict__ wt3,
                                               unsigned short* __restrict__ rank,
                                               unsigned short* __restrict__ percnt,
                                               unsigned int* __restrict__ zwords, int nzw) {
    __shared__ unsigned int cnt[HALF / 2];          // 50 KB (hist blocks only)
    const int b = blockIdx.x;
    const int tid = threadIdx.x;
    if (b < 128) {
        const int chunk = b & 63;
        const int dbase = (b >> 6) * HALF;
        for (int i = tid; i < HALF / 2; i += 1024) cnt[i] = 0;
        __syncthreads();
        const int e0 = chunk * CHUNK;
        for (int i = tid; i < CHUNK; i += 1024) {
            const int d = ei[NE + e0 + i];
            const int local = d - dbase;
            if ((unsigned)local < (unsigned)HALF) {
                const unsigned int old = atomicAdd(&cnt[local >> 1], 1u << ((local & 1) * 16));
                rank[e0 + i] = (unsigned short)((old >> ((local & 1) * 16)) & 0xFFFFu);
            }
        }
        __syncthreads();
        unsigned int* dst = (unsigned int*)&percnt[(size_t)chunk * NN + dbase];
        for (int i = tid; i < HALF / 2; i += 1024) dst[i] = cnt[i];
    } else if (b < 910) {
        const size_t base = ((size_t)(b - 128) * 1024 + tid) * 8;
        if (base < (size_t)NN * 128) {
            const float4 a = *(const float4*)&x[base];
            const float4 c = *(const float4*)&x[base + 4];
            uint4 o;
            o.x = (unsigned int)f2bf(a.x) | ((unsigned int)f2bf(a.y) << 16);
            o.y = (unsigned int)f2bf(a.z) | ((unsigned int)f2bf(a.w) << 16);
            o.z = (unsigned int)f2bf(c.x) | ((unsigned int)f2bf(c.y) << 16);
            o.w = (unsigned int)f2bf(c.z) | ((unsigned int)f2bf(c.w) << 16);
            *(uint4*)&xb[base] = o;
        }
    } else if (b == 910) {
        for (int o = tid; o < 128 * 128; o += 1024) {
            const int n = o >> 7;
            const int k = o & 127;
            wt1[o] = f2bf(W1[(size_t)k * 128 + n]);
            wt2[o] = f2bf(W2[(size_t)k * 128 + n]);
        }
        for (int o = tid; o < 64 * 128; o += 1024) {
            const int n = o >> 7;
            const int k = o & 127;
            wt3[o] = f2bf(W3[(size_t)k * 64 + n]);
        }
    } else {
        for (int i = tid; i < nzw; i += 1024) zwords[i] = 0;
    }
}

// ---------------- per-dst chunk scan (fence-free) ----------------
__global__ __launch_bounds__(256) void k_colscan(unsigned short* __restrict__ percnt,
                                                 int* __restrict__ degcnt, float* __restrict__ dinv) {
    const int d = blockIdx.x * 256 + threadIdx.x;
    if (d >= NN) return;
    int acc = 0;
#pragma unroll 8
    for (int b = 0; b < NCHUNK; ++b) {
        const int c = percnt[(size_t)b * NN + d];
        percnt[(size_t)b * NN + d] = (unsigned short)acc;
        acc += c;
    }
    degcnt[d] = acc;
    dinv[d] = (float)(1.0 / sqrt((double)acc + 1.0));
}

// ---------------- global exclusive scan, SINGLE block, NO per-thread array (no scratch spill) ----------------
__global__ __launch_bounds__(1024) void k_scan_all(const int* __restrict__ degcnt, int* __restrict__ row_ptr) {
    constexpr int PER = (NN + 1023) / 1024;   // 49
    const int tid = threadIdx.x;
    const int base = tid * PER;
    // pass 1: per-thread sum (no storage -> no spill; degcnt is L2-hot)
    int sum = 0;
    for (int i = 0; i < PER; ++i) {
        const int idx = base + i;
        if (idx < NN) sum += degcnt[idx];
    }
    __shared__ int ps[1024];
    ps[tid] = sum;
    __syncthreads();
    for (int off = 1; off < 1024; off <<= 1) {
        const int t = (tid >= off) ? ps[tid - off] : 0;
        __syncthreads();
        ps[tid] += t;
        __syncthreads();
    }
    // pass 2: re-read degcnt (L2-hit) and emit exclusive prefix
    int run = ps[tid] - sum;
    for (int i = 0; i < PER; ++i) {
        const int idx = base + i;
        if (idx < NN) {
            row_ptr[idx] = run;
            run += degcnt[idx];
        }
    }
    if (tid == 0) row_ptr[NN] = NE;
}

// ---------------- CSR fill: atomic-free ----------------
__global__ __launch_bounds__(256) void k_fill3(const int* __restrict__ ei, const int* __restrict__ row_ptr,
                                               const unsigned short* __restrict__ rank,
                                               const unsigned short* __restrict__ offs,
                                               int* __restrict__ csr_src) {
    const int e = blockIdx.x * 256 + threadIdx.x;
    if (e >= NE) return;
    const int s = ei[e];
    const int d = ei[NE + e];
    const int b = e / CHUNK;
    const int pos = row_ptr[d] + (int)offs[(size_t)b * NN + d] + (int)rank[e];
    csr_src[pos] = s;
}

// ---------------- bf16 MFMA GEMM: C[M x DO](bf16) = A[M x 128](bf16) @ Wt[DO x 128](bf16) ----------------
template <int DO>
__global__ __launch_bounds__(256) void k_gemm_mfma(const unsigned short* __restrict__ A,
                                                   const unsigned short* __restrict__ WtG,
                                                   unsigned short* __restrict__ C, int M) {
    constexpr int NT = DO / 16;
    constexpr int LDK = 136;
    __shared__ __align__(16) unsigned short As[64 * LDK];
    __shared__ __align__(16) unsigned short Ws[DO * LDK];
    const int tid = threadIdx.x;
    const int row0 = blockIdx.x * 64;

    for (int task = tid; task < DO * 16; task += 256) {
        const int n = task >> 4;
        const int ko = (task & 15) * 8;
        *(uint4*)&Ws[n * LDK + ko] = *(const uint4*)&WtG[(size_t)n * 128 + ko];
    }
    {
        const int r = tid >> 2;
        const int c0 = (tid & 3) * 32;
        const int grow = row0 + r;
#pragma unroll
        for (int q = 0; q < 4; ++q) {
            uint4 v = make_uint4(0, 0, 0, 0);
            if (grow < M) v = *(const uint4*)&A[(size_t)grow * 128 + c0 + q * 8];
            *(uint4*)&As[r * LDK + c0 + q * 8] = v;
        }
    }
    __syncthreads();

    const int l = tid & 63;
    const int w = tid >> 6;
    const int lr = l & 15;
    const int lg = l >> 4;
    f32x4 acc[NT];
#pragma unroll
    for (int nt = 0; nt < NT; ++nt) acc[nt] = (f32x4){0.f, 0.f, 0.f, 0.f};

#pragma unroll
    for (int kk = 0; kk < 128; kk += 32) {
        const short8 af = *(const short8*)&As[(w * 16 + lr) * LDK + kk + lg * 8];
#pragma unroll
        for (int nt = 0; nt < NT; ++nt) {
            const short8 bfv = *(const short8*)&Ws[(nt * 16 + lr) * LDK + kk + lg * 8];
            acc[nt] = __builtin_amdgcn_mfma_f32_16x16x32_bf16(af, bfv, acc[nt], 0, 0, 0);
        }
    }

#pragma unroll
    for (int nt = 0; nt < NT; ++nt) {
#pragma unroll
        for (int r = 0; r < 4; ++r) {
            const int grow = row0 + w * 16 + lg * 4 + r;
            if (grow < M) C[(size_t)grow * DO + nt * 16 + lr] = f2bf(acc[nt][r]);
        }
    }
}

// ---------------- aggregation (16B gathers, 8-way unroll, f32 accum, bf16 in/out) ----------------
template <int D, bool RELU>
__global__ __launch_bounds__(256) void k_agg(const unsigned short* __restrict__ T, const float* __restrict__ bias,
                                             const float* __restrict__ dinv, const int* __restrict__ row_ptr,
                                             const int* __restrict__ csr_src,
                                             unsigned short* __restrict__ out) {
    constexpr int G = D / 8;        // 16 (D=128) / 8 (D=64)
    constexpr int NPB = 256 / G;    // 16 / 32 nodes per block
    const int tid = threadIdx.x;
    const int lane = tid % G;
    const int grp = tid / G;
    const int n = blockIdx.x * NPB + grp;
    if (n >= NN) return;
    const int f0 = lane * 8;

    const float di_n = dinv[n];
    float acc[8] = {0.f, 0.f, 0.f, 0.f, 0.f, 0.f, 0.f, 0.f};
    const int beg = row_ptr[n];
    const int end = row_ptr[n + 1];
    int e = beg;
    for (; e + 8 <= end; e += 8) {
        int s[8];
        float wv[8];
#pragma unroll
        for (int j = 0; j < 8; ++j) s[j] = csr_src[e + j];
#pragma unroll
        for (int j = 0; j < 8; ++j) wv[j] = dinv[s[j]] * di_n;
        uint4 v[8];
#pragma unroll
        for (int j = 0; j < 8; ++j) v[j] = *(const uint4*)&T[(size_t)s[j] * D + f0];
#pragma unroll
        for (int j = 0; j < 8; ++j) fma8(acc, wv[j], v[j]);
    }
    for (; e + 4 <= end; e += 4) {
        const int s0 = csr_src[e + 0], s1 = csr_src[e + 1], s2 = csr_src[e + 2], s3 = csr_src[e + 3];
        const float w0 = dinv[s0] * di_n, w1 = dinv[s1] * di_n, w2 = dinv[s2] * di_n, w3 = dinv[s3] * di_n;
        const uint4 v0 = *(const uint4*)&T[(size_t)s0 * D + f0];
        const uint4 v1 = *(const uint4*)&T[(size_t)s1 * D + f0];
        const uint4 v2 = *(const uint4*)&T[(size_t)s2 * D + f0];
        const uint4 v3 = *(const uint4*)&T[(size_t)s3 * D + f0];
        fma8(acc, w0, v0);
        fma8(acc, w1, v1);
        fma8(acc, w2, v2);
        fma8(acc, w3, v3);
    }
    for (; e < end; ++e) {
        const int s = csr_src[e];
        const float w = dinv[s] * di_n;
        const uint4 v = *(const uint4*)&T[(size_t)s * D + f0];
        fma8(acc, w, v);
    }
    // self-loop
    {
        const uint4 v = *(const uint4*)&T[(size_t)n * D + f0];
        fma8(acc, di_n * di_n, v);
    }
    // bias
    const float4 b0 = *(const float4*)&bias[f0];
    const float4 b1 = *(const float4*)&bias[f0 + 4];
    acc[0] += b0.x; acc[1] += b0.y; acc[2] += b0.z; acc[3] += b0.w;
    acc[4] += b1.x; acc[5] += b1.y; acc[6] += b1.z; acc[7] += b1.w;
    if (RELU) {
#pragma unroll
        for (int j = 0; j < 8; ++j) acc[j] = fmaxf(acc[j], 0.f);
    }
    uint4 o;
    o.x = (unsigned int)f2bf(acc[0]) | ((unsigned int)f2bf(acc[1]) << 16);
    o.y = (unsigned int)f2bf(acc[2]) | ((unsigned int)f2bf(acc[3]) << 16);
    o.z = (unsigned int)f2bf(acc[4]) | ((unsigned int)f2bf(acc[5]) << 16);
    o.w = (unsigned int)f2bf(acc[6]) | ((unsigned int)f2bf(acc[7]) << 16);
    *(uint4*)&out[(size_t)n * D + f0] = o;
}

// ---------------- mean pool (batch sorted), bf16 input, f64 accum ----------------
__global__ __launch_bounds__(256) void k_pool(const unsigned short* __restrict__ h, const int* __restrict__ batch,
                                              double* __restrict__ sums, int* __restrict__ cnts) {
    const int NB = 256;
    const int n0 = blockIdx.x * NB;
    const int d = threadIdx.x & 63;
    const int sub = threadIdx.x >> 6;
    double acc = 0.0;
    int cnt = 0;
    int cur = -1;
    for (int i = sub; i < NB; i += 4) {
        int n = n0 + i;
        if (n >= NN) break;
        int g = batch[n];
        if (g != cur) {
            if (cur >= 0) {
                atomicAdd(&sums[cur * 64 + d], acc);
                if (d == 0) atomicAdd(&cnts[cur], cnt);
            }
            cur = g;
            acc = 0.0;
            cnt = 0;
        }
        acc += (double)bf2f(h[(size_t)n * 64 + d]);
        cnt++;
    }
    if (cur >= 0) {
        atomicAdd(&sums[cur * 64 + d], acc);
        if (d == 0) atomicAdd(&cnts[cur], cnt);
    }
}

__global__ __launch_bounds__(256) void k_final(const double* __restrict__ sums, const int* __restrict__ cnts,
                                               float* __restrict__ out) {
    int i = blockIdx.x * 256 + threadIdx.x;
    if (i >= NG * 64) return;
    int g = i >> 6;
    double c = (double)max(cnts[g], 1);
    out[i] = (float)(sums[i] / c);
}

extern "C" void kernel_launch(void* const* d_in, const int* in_sizes, int n_in,
                              void* d_out, int out_size, void* d_ws, size_t ws_size,
                              hipStream_t stream) {
    (void)in_sizes; (void)n_in; (void)out_size; (void)ws_size;
    const float* x     = (const float*)d_in[0];
    const int*   ei    = (const int*)d_in[1];
    const int*   batch = (const int*)d_in[2];
    const float* W1    = (const float*)d_in[3];
    const float* b1    = (const float*)d_in[4];
    const float* W2    = (const float*)d_in[5];
    const float* b2    = (const float*)d_in[6];
    const float* W3    = (const float*)d_in[7];
    const float* b3    = (const float*)d_in[8];
    float* out = (float*)d_out;

    // workspace layout
    char* w = (char*)d_ws;
    // zero region (cleared by k_prep block 911 each call): psums | pcnts
    char*  zbase = w;
    double* psums  = (double*)w;        w += (size_t)NG * 64 * 8;
    int*    pcnts  = (int*)w;           w += 256;
    const int nzw = (int)((w - zbase) / 4);
    int*    degcnt = (int*)w;           w += (size_t)NN * 4;
    float*  dinv   = (float*)w;         w += (size_t)NN * 4;
    int*    row_ptr = (int*)w;          w += (size_t)(NN + 4) * 4;
    unsigned short* wt1 = (unsigned short*)w;  w += 128 * 128 * 2;
    unsigned short* wt2 = (unsigned short*)w;  w += 128 * 128 * 2;
    unsigned short* wt3 = (unsigned short*)w;  w += 64 * 128 * 2;
    unsigned short* rank   = (unsigned short*)w;  w += (size_t)NE * 2;
    unsigned short* percnt = (unsigned short*)w;  w += (size_t)NCHUNK * NN * 2;
    int*    csr_src = (int*)w;          w += (size_t)NE * 4;
    unsigned short* xb   = (unsigned short*)w;  w += (size_t)NN * 128 * 2;
    unsigned short* bufT = (unsigned short*)w;  w += (size_t)NN * 128 * 2;
    unsigned short* bufA = (unsigned short*)w;  w += (size_t)NN * 128 * 2;

    // fused front-end (1 dispatch, no cross-block coordination)
    k_prep<<<912, 1024, 0, stream>>>(x, W1, W2, W3, ei, xb, wt1, wt2, wt3, rank, percnt,
                                     (unsigned int*)zbase, nzw);
    k_colscan<<<(NN + 255) / 256, 256, 0, stream>>>(percnt, degcnt, dinv);
    k_scan_all<<<1, 1024, 0, stream>>>(degcnt, row_ptr);
    k_fill3<<<(NE + 255) / 256, 256, 0, stream>>>(ei, row_ptr, rank, percnt, csr_src);

    const int gemm_grid = (NN + 63) / 64;      // 782
    const int agg_grid128 = (NN + 15) / 16;    // 3125
    const int agg_grid64  = (NN + 31) / 32;    // 1563
    // layer 1
    k_gemm_mfma<128><<<gemm_grid, 256, 0, stream>>>(xb, wt1, bufT, NN);
    k_agg<128, true><<<agg_grid128, 256, 0, stream>>>(bufT, b1, dinv, row_ptr, csr_src, bufA);
    // layer 2
    k_gemm_mfma<128><<<gemm_grid, 256, 0, stream>>>(bufA, wt2, bufT, NN);
    k_agg<128, true><<<agg_grid128, 256, 0, stream>>>(bufT, b2, dinv, row_ptr, csr_src, bufA);
    // layer 3 (no relu, D_OUT=64)
    k_gemm_mfma<64><<<gemm_grid, 256, 0, stream>>>(bufA, wt3, bufT, NN);
    k_agg<64, false><<<agg_grid64, 256, 0, stream>>>(bufT, b3, dinv, row_ptr, csr_src, bufA);
    // pool
    k_pool<<<(NN + 255) / 256, 256, 0, stream>>>(bufA, batch, psums, pcnts);
    k_final<<<(NG * 64 + 255) / 256, 256, 0, stream>>>(psums, pcnts, out);
}

// Round 16
// 239.091 us; speedup vs baseline: 1.3544x; 1.3544x over previous
//
#include <hip/hip_runtime.h>

#define NN 50000
#define NE 800000
#define NG 64
#define NCHUNK 64
#define CHUNK 12500     // NE / NCHUNK
#define HALF 25000      // NN / 2

typedef short short8 __attribute__((ext_vector_type(8)));
typedef float f32x4 __attribute__((ext_vector_type(4)));

// bf16 helpers (RTNE)
__device__ __forceinline__ unsigned short f2bf(float f) {
    unsigned int u = __float_as_uint(f);
    u = (u + 0x7FFFu + ((u >> 16) & 1u)) >> 16;
    return (unsigned short)u;
}
__device__ __forceinline__ float bf2f(unsigned short h) {
    return __uint_as_float((unsigned int)h << 16);
}
// accumulate 8 bf16 feats (one uint4) with weight w
__device__ __forceinline__ void fma8(float* acc, float w, const uint4 v) {
    const unsigned int u0 = v.x, u1 = v.y, u2 = v.z, u3 = v.w;
    acc[0] = fmaf(w, __uint_as_float(u0 << 16), acc[0]);
    acc[1] = fmaf(w, __uint_as_float(u0 & 0xFFFF0000u), acc[1]);
    acc[2] = fmaf(w, __uint_as_float(u1 << 16), acc[2]);
    acc[3] = fmaf(w, __uint_as_float(u1 & 0xFFFF0000u), acc[3]);
    acc[4] = fmaf(w, __uint_as_float(u2 << 16), acc[4]);
    acc[5] = fmaf(w, __uint_as_float(u2 & 0xFFFF0000u), acc[5]);
    acc[6] = fmaf(w, __uint_as_float(u3 << 16), acc[6]);
    acc[7] = fmaf(w, __uint_as_float(u3 & 0xFFFF0000u), acc[7]);
}

// ---------------- fused front-end: hist | cvtx | cvtw | zero (no cross-block coordination) ----------------
__global__ __launch_bounds__(1024) void k_prep(const float* __restrict__ x, const float* __restrict__ W1,
                                               const float* __restrict__ W2, const float* __restrict__ W3,
                                               const int* __restrict__ ei,
                                               unsigned short* __restrict__ xb,
                                               unsigned short* __restrict__ wt1, unsigned short* __restrict__ wt2,
                                               unsigned short* __restrict__ wt3,
                                               unsigned short* __restrict__ rank,
                                               unsigned short* __restrict__ percnt,
                                               unsigned int* __restrict__ zwords, int nzw) {
    __shared__ unsigned int cnt[HALF / 2];          // 50 KB (hist blocks only)
    const int b = blockIdx.x;
    const int tid = threadIdx.x;
    if (b < 128) {
        const int chunk = b & 63;
        const int dbase = (b >> 6) * HALF;
        for (int i = tid; i < HALF / 2; i += 1024) cnt[i] = 0;
        __syncthreads();
        const int e0 = chunk * CHUNK;
        for (int i = tid; i < CHUNK; i += 1024) {
            const int d = ei[NE + e0 + i];
            const int local = d - dbase;
            if ((unsigned)local < (unsigned)HALF) {
                const unsigned int old = atomicAdd(&cnt[local >> 1], 1u << ((local & 1) * 16));
                rank[e0 + i] = (unsigned short)((old >> ((local & 1) * 16)) & 0xFFFFu);
            }
        }
        __syncthreads();
        unsigned int* dst = (unsigned int*)&percnt[(size_t)chunk * NN + dbase];
        for (int i = tid; i < HALF / 2; i += 1024) dst[i] = cnt[i];
    } else if (b < 910) {
        const size_t base = ((size_t)(b - 128) * 1024 + tid) * 8;
        if (base < (size_t)NN * 128) {
            const float4 a = *(const float4*)&x[base];
            const float4 c = *(const float4*)&x[base + 4];
            uint4 o;
            o.x = (unsigned int)f2bf(a.x) | ((unsigned int)f2bf(a.y) << 16);
            o.y = (unsigned int)f2bf(a.z) | ((unsigned int)f2bf(a.w) << 16);
            o.z = (unsigned int)f2bf(c.x) | ((unsigned int)f2bf(c.y) << 16);
            o.w = (unsigned int)f2bf(c.z) | ((unsigned int)f2bf(c.w) << 16);
            *(uint4*)&xb[base] = o;
        }
    } else if (b == 910) {
        for (int o = tid; o < 128 * 128; o += 1024) {
            const int n = o >> 7;
            const int k = o & 127;
            wt1[o] = f2bf(W1[(size_t)k * 128 + n]);
            wt2[o] = f2bf(W2[(size_t)k * 128 + n]);
        }
        for (int o = tid; o < 64 * 128; o += 1024) {
            const int n = o >> 7;
            const int k = o & 127;
            wt3[o] = f2bf(W3[(size_t)k * 64 + n]);
        }
    } else {
        for (int i = tid; i < nzw; i += 1024) zwords[i] = 0;
    }
}

// ---------------- per-dst chunk scan (fence-free) ----------------
__global__ __launch_bounds__(256) void k_colscan(unsigned short* __restrict__ percnt,
                                                 int* __restrict__ degcnt, float* __restrict__ dinv) {
    const int d = blockIdx.x * 256 + threadIdx.x;
    if (d >= NN) return;
    int acc = 0;
#pragma unroll 8
    for (int b = 0; b < NCHUNK; ++b) {
        const int c = percnt[(size_t)b * NN + d];
        percnt[(size_t)b * NN + d] = (unsigned short)acc;
        acc += c;
    }
    degcnt[d] = acc;
    dinv[d] = (float)(1.0 / sqrt((double)acc + 1.0));
}

// ---------------- prefix scan (3 stages, round-11 proven) ----------------
__global__ __launch_bounds__(1024) void k_scan1(const int* __restrict__ cnt, int* __restrict__ row_ptr,
                                                int* __restrict__ blk_sums) {
    __shared__ int s[1024];
    const int tid = threadIdx.x;
    const int i = blockIdx.x * 1024 + tid;
    int v = (i < NN) ? cnt[i] : 0;
    s[tid] = v;
    __syncthreads();
    for (int off = 1; off < 1024; off <<= 1) {
        int t = (tid >= off) ? s[tid - off] : 0;
        __syncthreads();
        s[tid] += t;
        __syncthreads();
    }
    if (i < NN) row_ptr[i] = s[tid] - v;
    if (tid == 1023) blk_sums[blockIdx.x] = s[1023];
}

__global__ __launch_bounds__(64) void k_scan2(int* __restrict__ blk_sums, int nb) {
    int l = threadIdx.x;
    int v = (l < nb) ? blk_sums[l] : 0;
    int incl = v;
    for (int off = 1; off < 64; off <<= 1) {
        int t = __shfl_up(incl, off, 64);
        if (l >= off) incl += t;
    }
    if (l < nb) blk_sums[l] = incl - v;
}

__global__ __launch_bounds__(1024) void k_scan3(int* __restrict__ row_ptr, const int* __restrict__ blk_sums) {
    int i = blockIdx.x * 1024 + threadIdx.x;
    if (i < NN) row_ptr[i] += blk_sums[blockIdx.x];
    if (i == 0) row_ptr[NN] = NE;
}

// ---------------- CSR fill: atomic-free ----------------
__global__ __launch_bounds__(256) void k_fill3(const int* __restrict__ ei, const int* __restrict__ row_ptr,
                                               const unsigned short* __restrict__ rank,
                                               const unsigned short* __restrict__ offs,
                                               int* __restrict__ csr_src) {
    const int e = blockIdx.x * 256 + threadIdx.x;
    if (e >= NE) return;
    const int s = ei[e];
    const int d = ei[NE + e];
    const int b = e / CHUNK;
    const int pos = row_ptr[d] + (int)offs[(size_t)b * NN + d] + (int)rank[e];
    csr_src[pos] = s;
}

// ---------------- bf16 MFMA GEMM: C[M x DO](bf16) = A[M x 128](bf16) @ Wt[DO x 128](bf16) ----------------
template <int DO>
__global__ __launch_bounds__(256) void k_gemm_mfma(const unsigned short* __restrict__ A,
                                                   const unsigned short* __restrict__ WtG,
                                                   unsigned short* __restrict__ C, int M) {
    constexpr int NT = DO / 16;
    constexpr int LDK = 136;
    __shared__ __align__(16) unsigned short As[64 * LDK];
    __shared__ __align__(16) unsigned short Ws[DO * LDK];
    const int tid = threadIdx.x;
    const int row0 = blockIdx.x * 64;

    for (int task = tid; task < DO * 16; task += 256) {
        const int n = task >> 4;
        const int ko = (task & 15) * 8;
        *(uint4*)&Ws[n * LDK + ko] = *(const uint4*)&WtG[(size_t)n * 128 + ko];
    }
    {
        const int r = tid >> 2;
        const int c0 = (tid & 3) * 32;
        const int grow = row0 + r;
#pragma unroll
        for (int q = 0; q < 4; ++q) {
            uint4 v = make_uint4(0, 0, 0, 0);
            if (grow < M) v = *(const uint4*)&A[(size_t)grow * 128 + c0 + q * 8];
            *(uint4*)&As[r * LDK + c0 + q * 8] = v;
        }
    }
    __syncthreads();

    const int l = tid & 63;
    const int w = tid >> 6;
    const int lr = l & 15;
    const int lg = l >> 4;
    f32x4 acc[NT];
#pragma unroll
    for (int nt = 0; nt < NT; ++nt) acc[nt] = (f32x4){0.f, 0.f, 0.f, 0.f};

#pragma unroll
    for (int kk = 0; kk < 128; kk += 32) {
        const short8 af = *(const short8*)&As[(w * 16 + lr) * LDK + kk + lg * 8];
#pragma unroll
        for (int nt = 0; nt < NT; ++nt) {
            const short8 bfv = *(const short8*)&Ws[(nt * 16 + lr) * LDK + kk + lg * 8];
            acc[nt] = __builtin_amdgcn_mfma_f32_16x16x32_bf16(af, bfv, acc[nt], 0, 0, 0);
        }
    }

#pragma unroll
    for (int nt = 0; nt < NT; ++nt) {
#pragma unroll
        for (int r = 0; r < 4; ++r) {
            const int grow = row0 + w * 16 + lg * 4 + r;
            if (grow < M) C[(size_t)grow * DO + nt * 16 + lr] = f2bf(acc[nt][r]);
        }
    }
}

// ---------------- aggregation (16B gathers, 8-way unroll, f32 accum, bf16 in/out) ----------------
template <int D, bool RELU>
__global__ __launch_bounds__(256) void k_agg(const unsigned short* __restrict__ T, const float* __restrict__ bias,
                                             const float* __restrict__ dinv, const int* __restrict__ row_ptr,
                                             const int* __restrict__ csr_src,
                                             unsigned short* __restrict__ out) {
    constexpr int G = D / 8;        // 16 (D=128) / 8 (D=64)
    constexpr int NPB = 256 / G;    // 16 / 32 nodes per block
    const int tid = threadIdx.x;
    const int lane = tid % G;
    const int grp = tid / G;
    const int n = blockIdx.x * NPB + grp;
    if (n >= NN) return;
    const int f0 = lane * 8;

    const float di_n = dinv[n];
    float acc[8] = {0.f, 0.f, 0.f, 0.f, 0.f, 0.f, 0.f, 0.f};
    const int beg = row_ptr[n];
    const int end = row_ptr[n + 1];
    int e = beg;
    for (; e + 8 <= end; e += 8) {
        int s[8];
        float wv[8];
#pragma unroll
        for (int j = 0; j < 8; ++j) s[j] = csr_src[e + j];
#pragma unroll
        for (int j = 0; j < 8; ++j) wv[j] = dinv[s[j]] * di_n;
        uint4 v[8];
#pragma unroll
        for (int j = 0; j < 8; ++j) v[j] = *(const uint4*)&T[(size_t)s[j] * D + f0];
#pragma unroll
        for (int j = 0; j < 8; ++j) fma8(acc, wv[j], v[j]);
    }
    for (; e + 4 <= end; e += 4) {
        const int s0 = csr_src[e + 0], s1 = csr_src[e + 1], s2 = csr_src[e + 2], s3 = csr_src[e + 3];
        const float w0 = dinv[s0] * di_n, w1 = dinv[s1] * di_n, w2 = dinv[s2] * di_n, w3 = dinv[s3] * di_n;
        const uint4 v0 = *(const uint4*)&T[(size_t)s0 * D + f0];
        const uint4 v1 = *(const uint4*)&T[(size_t)s1 * D + f0];
        const uint4 v2 = *(const uint4*)&T[(size_t)s2 * D + f0];
        const uint4 v3 = *(const uint4*)&T[(size_t)s3 * D + f0];
        fma8(acc, w0, v0);
        fma8(acc, w1, v1);
        fma8(acc, w2, v2);
        fma8(acc, w3, v3);
    }
    for (; e < end; ++e) {
        const int s = csr_src[e];
        const float w = dinv[s] * di_n;
        const uint4 v = *(const uint4*)&T[(size_t)s * D + f0];
        fma8(acc, w, v);
    }
    // self-loop
    {
        const uint4 v = *(const uint4*)&T[(size_t)n * D + f0];
        fma8(acc, di_n * di_n, v);
    }
    // bias
    const float4 b0 = *(const float4*)&bias[f0];
    const float4 b1 = *(const float4*)&bias[f0 + 4];
    acc[0] += b0.x; acc[1] += b0.y; acc[2] += b0.z; acc[3] += b0.w;
    acc[4] += b1.x; acc[5] += b1.y; acc[6] += b1.z; acc[7] += b1.w;
    if (RELU) {
#pragma unroll
        for (int j = 0; j < 8; ++j) acc[j] = fmaxf(acc[j], 0.f);
    }
    uint4 o;
    o.x = (unsigned int)f2bf(acc[0]) | ((unsigned int)f2bf(acc[1]) << 16);
    o.y = (unsigned int)f2bf(acc[2]) | ((unsigned int)f2bf(acc[3]) << 16);
    o.z = (unsigned int)f2bf(acc[4]) | ((unsigned int)f2bf(acc[5]) << 16);
    o.w = (unsigned int)f2bf(acc[6]) | ((unsigned int)f2bf(acc[7]) << 16);
    *(uint4*)&out[(size_t)n * D + f0] = o;
}

// ---------------- mean pool (batch sorted), bf16 input, f64 accum ----------------
__global__ __launch_bounds__(256) void k_pool(const unsigned short* __restrict__ h, const int* __restrict__ batch,
                                              double* __restrict__ sums, int* __restrict__ cnts) {
    const int NB = 256;
    const int n0 = blockIdx.x * NB;
    const int d = threadIdx.x & 63;
    const int sub = threadIdx.x >> 6;
    double acc = 0.0;
    int cnt = 0;
    int cur = -1;
    for (int i = sub; i < NB; i += 4) {
        int n = n0 + i;
        if (n >= NN) break;
        int g = batch[n];
        if (g != cur) {
            if (cur >= 0) {
                atomicAdd(&sums[cur * 64 + d], acc);
                if (d == 0) atomicAdd(&cnts[cur], cnt);
            }
            cur = g;
            acc = 0.0;
            cnt = 0;
        }
        acc += (double)bf2f(h[(size_t)n * 64 + d]);
        cnt++;
    }
    if (cur >= 0) {
        atomicAdd(&sums[cur * 64 + d], acc);
        if (d == 0) atomicAdd(&cnts[cur], cnt);
    }
}

__global__ __launch_bounds__(256) void k_final(const double* __restrict__ sums, const int* __restrict__ cnts,
                                               float* __restrict__ out) {
    int i = blockIdx.x * 256 + threadIdx.x;
    if (i >= NG * 64) return;
    int g = i >> 6;
    double c = (double)max(cnts[g], 1);
    out[i] = (float)(sums[i] / c);
}

extern "C" void kernel_launch(void* const* d_in, const int* in_sizes, int n_in,
                              void* d_out, int out_size, void* d_ws, size_t ws_size,
                              hipStream_t stream) {
    (void)in_sizes; (void)n_in; (void)out_size; (void)ws_size;
    const float* x     = (const float*)d_in[0];
    const int*   ei    = (const int*)d_in[1];
    const int*   batch = (const int*)d_in[2];
    const float* W1    = (const float*)d_in[3];
    const float* b1    = (const float*)d_in[4];
    const float* W2    = (const float*)d_in[5];
    const float* b2    = (const float*)d_in[6];
    const float* W3    = (const float*)d_in[7];
    const float* b3    = (const float*)d_in[8];
    float* out = (float*)d_out;

    // workspace layout
    char* w = (char*)d_ws;
    // zero region (cleared by k_prep block 911 each call): psums | pcnts
    char*  zbase = w;
    double* psums  = (double*)w;        w += (size_t)NG * 64 * 8;
    int*    pcnts  = (int*)w;           w += 256;
    const int nzw = (int)((w - zbase) / 4);
    int*    degcnt = (int*)w;           w += (size_t)NN * 4;
    float*  dinv   = (float*)w;         w += (size_t)NN * 4;
    int*    row_ptr = (int*)w;          w += (size_t)(NN + 4) * 4;
    int*    blk_sums = (int*)w;         w += 64 * 4;
    unsigned short* wt1 = (unsigned short*)w;  w += 128 * 128 * 2;
    unsigned short* wt2 = (unsigned short*)w;  w += 128 * 128 * 2;
    unsigned short* wt3 = (unsigned short*)w;  w += 64 * 128 * 2;
    unsigned short* rank   = (unsigned short*)w;  w += (size_t)NE * 2;
    unsigned short* percnt = (unsigned short*)w;  w += (size_t)NCHUNK * NN * 2;
    int*    csr_src = (int*)w;          w += (size_t)NE * 4;
    unsigned short* xb   = (unsigned short*)w;  w += (size_t)NN * 128 * 2;
    unsigned short* bufT = (unsigned short*)w;  w += (size_t)NN * 128 * 2;
    unsigned short* bufA = (unsigned short*)w;  w += (size_t)NN * 128 * 2;

    // fused front-end (1 dispatch, no cross-block coordination)
    k_prep<<<912, 1024, 0, stream>>>(x, W1, W2, W3, ei, xb, wt1, wt2, wt3, rank, percnt,
                                     (unsigned int*)zbase, nzw);
    k_colscan<<<(NN + 255) / 256, 256, 0, stream>>>(percnt, degcnt, dinv);
    const int nb_scan = (NN + 1023) / 1024;   // 49
    k_scan1<<<nb_scan, 1024, 0, stream>>>(degcnt, row_ptr, blk_sums);
    k_scan2<<<1, 64, 0, stream>>>(blk_sums, nb_scan);
    k_scan3<<<nb_scan, 1024, 0, stream>>>(row_ptr, blk_sums);
    k_fill3<<<(NE + 255) / 256, 256, 0, stream>>>(ei, row_ptr, rank, percnt, csr_src);

    const int gemm_grid = (NN + 63) / 64;      // 782
    const int agg_grid128 = (NN + 15) / 16;    // 3125
    const int agg_grid64  = (NN + 31) / 32;    // 1563
    // layer 1
    k_gemm_mfma<128><<<gemm_grid, 256, 0, stream>>>(xb, wt1, bufT, NN);
    k_agg<128, true><<<agg_grid128, 256, 0, stream>>>(bufT, b1, dinv, row_ptr, csr_src, bufA);
    // layer 2
    k_gemm_mfma<128><<<gemm_grid, 256, 0, stream>>>(bufA, wt2, bufT, NN);
    k_agg<128, true><<<agg_grid128, 256, 0, stream>>>(bufT, b2, dinv, row_ptr, csr_src, bufA);
    // layer 3 (no relu, D_OUT=64)
    k_gemm_mfma<64><<<gemm_grid, 256, 0, stream>>>(bufA, wt3, bufT, NN);
    k_agg<64, false><<<agg_grid64, 256, 0, stream>>>(bufT, b3, dinv, row_ptr, csr_src, bufA);
    // pool
    k_pool<<<(NN + 255) / 256, 256, 0, stream>>>(bufA, batch, psums, pcnts);
    k_final<<<(NG * 64 + 255) / 256, 256, 0, stream>>>(psums, pcnts, out);
}